// Round 3
// baseline (3037.238 us; speedup 1.0000x reference)
//
#include <hip/hip_runtime.h>
#include <math.h>

#define DEV __device__ __forceinline__

static constexpr int B_ = 128, T_ = 32, H_ = 512;
static constexpr int S_ = 2048, M_ = 64, OUT_ = 256;
static constexpr int VC_ = 712;   // 256 (vt) + 453 (ctrl), padded to 712
static constexpr float EPSF = 1e-8f;

DEV float sigmoidf_(float x){ return 1.0f/(1.0f+expf(-x)); }
DEV float softplusf_(float x){ return fmaxf(x,0.0f) + log1pf(expf(-fabsf(x))); }

// ---- packed candidate: (monotonic(value) << 32) | ~idx  => u64 '>' == (value desc, idx asc)
DEV unsigned long long packCand(float v, unsigned idx){
  unsigned u = __float_as_uint(v);
  unsigned m = (u & 0x80000000u) ? ~u : (u | 0x80000000u);
  return ((unsigned long long)m << 32) | (unsigned)(~idx);
}
DEV float unpackVal(unsigned long long e){
  unsigned m = (unsigned)(e >> 32);
  unsigned u = (m & 0x80000000u) ? (m & 0x7FFFFFFFu) : ~m;
  return __uint_as_float(u);
}
DEV unsigned unpackIdx(unsigned long long e){ return ~(unsigned)e; }

DEV void cswp(unsigned long long &a, unsigned long long &b){
  if(a < b){ unsigned long long t=a; a=b; b=t; }   // larger first (descending)
}
// Batcher odd-even mergesort for 8, descending
DEV void sort8(unsigned long long* L){
  cswp(L[0],L[1]); cswp(L[2],L[3]); cswp(L[4],L[5]); cswp(L[6],L[7]);
  cswp(L[0],L[2]); cswp(L[1],L[3]); cswp(L[4],L[6]); cswp(L[5],L[7]);
  cswp(L[1],L[2]); cswp(L[5],L[6]);
  cswp(L[0],L[4]); cswp(L[1],L[5]); cswp(L[2],L[6]); cswp(L[3],L[7]);
  cswp(L[2],L[4]); cswp(L[3],L[5]);
  cswp(L[1],L[2]); cswp(L[3],L[4]); cswp(L[5],L[6]);
}
// bitonic merge of 16, descending (input must be bitonic)
DEV void bmerge16(unsigned long long* C){
  #pragma unroll
  for(int i=0;i<8;i++) cswp(C[i],C[i+8]);
  #pragma unroll
  for(int g=0;g<2;g++){ int o=g*8;
    cswp(C[o+0],C[o+4]); cswp(C[o+1],C[o+5]); cswp(C[o+2],C[o+6]); cswp(C[o+3],C[o+7]); }
  #pragma unroll
  for(int g=0;g<4;g++){ int o=g*4; cswp(C[o+0],C[o+2]); cswp(C[o+1],C[o+3]); }
  #pragma unroll
  for(int g=0;g<8;g++){ int o=g*2; cswp(C[o],C[o+1]); }
}
// X[0..7] desc, X[8..15] desc -> X[0..15] fully sorted desc
DEV void merge8x8(unsigned long long* X){
  unsigned long long C[16];
  #pragma unroll
  for(int i=0;i<8;i++){ C[i]=X[i]; C[8+i]=X[15-i]; }
  bmerge16(C);
  #pragma unroll
  for(int i=0;i<16;i++) X[i]=C[i];
}
// A,B sorted-16 desc; A := sorted top-16 of union
DEV void keep16(unsigned long long* A, const unsigned long long* Bv){
  unsigned long long C[16];
  #pragma unroll
  for(int i=0;i<16;i++){ unsigned long long a=A[i], b=Bv[15-i]; C[i]=(a>b)?a:b; }
  bmerge16(C);
  #pragma unroll
  for(int i=0;i<16;i++) A[i]=C[i];
}
// butterfly keep-8: each lane holds sorted-8 desc
DEV void butterfly8(unsigned long long* L, int maxMask){
  for(int mask=1; mask<=maxMask; mask<<=1){
    unsigned long long O[8], C[8];
    #pragma unroll
    for(int i=0;i<8;i++) O[i] = __shfl_xor(L[i], mask, 64);
    #pragma unroll
    for(int i=0;i<8;i++){ unsigned long long a=L[i], b=O[7-i]; C[i] = (a>b)?a:b; }
    cswp(C[0],C[4]); cswp(C[1],C[5]); cswp(C[2],C[6]); cswp(C[3],C[7]);
    cswp(C[0],C[2]); cswp(C[1],C[3]); cswp(C[4],C[6]); cswp(C[5],C[7]);
    cswp(C[0],C[1]); cswp(C[2],C[3]); cswp(C[4],C[5]); cswp(C[6],C[7]);
    #pragma unroll
    for(int i=0;i<8;i++) L[i]=C[i];
  }
}
// butterfly keep-16 over all 64 lanes (per-lane lists sorted-16 desc)
DEV void butterfly16(unsigned long long* L){
  for(int mask=1; mask<64; mask<<=1){
    unsigned long long O[16], C[16];
    #pragma unroll
    for(int i=0;i<16;i++) O[i] = __shfl_xor(L[i], mask, 64);
    #pragma unroll
    for(int i=0;i<16;i++){ unsigned long long a=L[i], b=O[15-i]; C[i] = (a>b)?a:b; }
    bmerge16(C);
    #pragma unroll
    for(int i=0;i<16;i++) L[i]=C[i];
  }
}

// ---------------- preamble: W_rd [256,256] -> W_rdT ----------------
__global__ __launch_bounds__(256)
void k_transpose_rd(const float* __restrict__ W, float* __restrict__ WT){
  int idx = blockIdx.x*256 + threadIdx.x;  // 65536
  int k = idx>>8, o = idx&255;
  WT[k*256+o] = W[o*256+k];
}

// ---------------- generic fp32 GEMM  C[M,N] = A[M,K] * Bm[N,K]^T ----------------
__global__ __launch_bounds__(256)
void k_gemm64(const float* __restrict__ A, int lda,
              const float* __restrict__ Bm, int ldb,
              float* __restrict__ C, int ldc,
              int kCount,
              const float* __restrict__ bias0, const float* __restrict__ bias1)
{
  const int BM=64, BN=64, BK=16, LDT=68;
  __shared__ float As[BK*LDT];
  __shared__ float Bs[BK*LDT];
  const int m0 = blockIdx.x*BM, n0 = blockIdx.y*BN;
  const int tid = threadIdx.x;
  const int tx = tid & 15, ty = tid >> 4;
  const int kStart = blockIdx.z * kCount;
  float acc[4][4] = {};
  const int row = tid >> 2, kk = (tid & 3) * 4;
  for(int k0 = kStart; k0 < kStart + kCount; k0 += BK){
    float4 av = *(const float4*)(A  + (size_t)(m0+row)*lda + k0 + kk);
    float4 bv = *(const float4*)(Bm + (size_t)(n0+row)*ldb + k0 + kk);
    As[(kk+0)*LDT+row]=av.x; As[(kk+1)*LDT+row]=av.y; As[(kk+2)*LDT+row]=av.z; As[(kk+3)*LDT+row]=av.w;
    Bs[(kk+0)*LDT+row]=bv.x; Bs[(kk+1)*LDT+row]=bv.y; Bs[(kk+2)*LDT+row]=bv.z; Bs[(kk+3)*LDT+row]=bv.w;
    __syncthreads();
    #pragma unroll
    for(int k=0;k<BK;k++){
      float4 a = *(const float4*)&As[k*LDT + 4*ty];
      float4 b = *(const float4*)&Bs[k*LDT + 4*tx];
      acc[0][0]+=a.x*b.x; acc[0][1]+=a.x*b.y; acc[0][2]+=a.x*b.z; acc[0][3]+=a.x*b.w;
      acc[1][0]+=a.y*b.x; acc[1][1]+=a.y*b.y; acc[1][2]+=a.y*b.z; acc[1][3]+=a.y*b.w;
      acc[2][0]+=a.z*b.x; acc[2][1]+=a.z*b.y; acc[2][2]+=a.z*b.z; acc[2][3]+=a.z*b.w;
      acc[3][0]+=a.w*b.x; acc[3][1]+=a.w*b.y; acc[3][2]+=a.w*b.z; acc[3][3]+=a.w*b.w;
    }
    __syncthreads();
  }
  float* Cz = C + (size_t)blockIdx.z * (size_t)gridDim.x * BM * (size_t)ldc;
  #pragma unroll
  for(int i=0;i<4;i++){
    int m = m0 + 4*ty + i;
    int n = n0 + 4*tx;
    float4 o; o.x=acc[i][0]; o.y=acc[i][1]; o.z=acc[i][2]; o.w=acc[i][3];
    if(bias0){
      o.x += bias0[n]+bias1[n];     o.y += bias0[n+1]+bias1[n+1];
      o.z += bias0[n+2]+bias1[n+2]; o.w += bias0[n+3]+bias1[n+3];
    }
    *(float4*)(Cz + (size_t)m*ldc + n) = o;
  }
}

// ---------------- per-step: LSTM elementwise ----------------
__global__ __launch_bounds__(256)
void k_lstm(const float* __restrict__ xg, const float* __restrict__ gp,
            float* __restrict__ h, float* __restrict__ c, int t)
{
  int idx = blockIdx.x*256 + threadIdx.x;   // 65536 = 128*512
  int b = idx >> 9, j = idx & 511;
  const float* xr = xg + ((size_t)b*T_ + t)*(size_t)(4*H_);
  float gi = xr[j], gf = xr[512+j], gg = xr[1024+j], go = xr[1536+j];
  #pragma unroll
  for(int s4=0;s4<4;s4++){
    const float* pr = gp + ((size_t)s4*B_ + b)*(size_t)(4*H_);
    gi += pr[j]; gf += pr[512+j]; gg += pr[1024+j]; go += pr[1536+j];
  }
  float cc = sigmoidf_(gf)*c[idx] + sigmoidf_(gi)*tanhf(gg);
  float hh = sigmoidf_(go)*tanhf(cc);
  c[idx] = cc; h[idx] = hh;
}

// ---------------- per-step: vt+ctrl GEMM ----------------
__global__ __launch_bounds__(256)
void k_vtctrl(const float* __restrict__ h, const float* __restrict__ Wout,
              const float* __restrict__ bout, const float* __restrict__ Whead,
              const float* __restrict__ bhead, float* __restrict__ vc)
{
  const int BM=32, BN=32, BK=16, LDT=34;
  __shared__ float As[BK*LDT], Bs[BK*LDT];
  const int m0 = blockIdx.x*BM, n0 = blockIdx.y*BN;
  const int tid = threadIdx.x, tx = tid&15, ty = tid>>4;
  float acc[2][2] = {};
  for(int k0=0;k0<512;k0+=BK){
    #pragma unroll
    for(int p=0;p<2;p++){
      int idx = tid + p*256;
      int r = idx>>4, kq = idx&15;
      As[kq*LDT+r] = h[(size_t)(m0+r)*512 + k0+kq];
      int j = n0 + r;
      float v = 0.f;
      if(j < 256)      v = Wout[(size_t)j*512 + k0+kq];
      else if(j < 709) v = Whead[(size_t)(j-256)*512 + k0+kq];
      Bs[kq*LDT+r] = v;
    }
    __syncthreads();
    #pragma unroll
    for(int k=0;k<BK;k++){
      float2 a = *(const float2*)&As[k*LDT + 2*ty];
      float2 b = *(const float2*)&Bs[k*LDT + 2*tx];
      acc[0][0]+=a.x*b.x; acc[0][1]+=a.x*b.y; acc[1][0]+=a.y*b.x; acc[1][1]+=a.y*b.y;
    }
    __syncthreads();
  }
  #pragma unroll
  for(int i=0;i<2;i++){
    int m = m0 + 2*ty + i;
    #pragma unroll
    for(int j2=0;j2<2;j2++){
      int n = n0 + 2*tx + j2;
      if(n < VC_){
        float bv = 0.f;
        if(n < 256) bv = bout[n]; else if(n < 709) bv = bhead[n-256];
        vc[(size_t)m*VC_ + n] = (n < 709) ? acc[i][j2] + bv : 0.f;
      }
    }
  }
}

// ---------------- fused per-step kernel ----------------
// blocks 0..127   : scores+heads for batch b = blockIdx.x (all in-LDS, 4 waves)
// blocks 128..383 : gparts(t+1) = h @ W_hh^T tiles (same body as k_gemm64, split-K x4)
__global__ __launch_bounds__(256)
void k_fused(float* __restrict__ memC, const float* __restrict__ vc,
             const float* __restrict__ h, const float* __restrict__ W_hh,
             float* __restrict__ gparts,
             const float* __restrict__ WrdT, const float* __restrict__ b_rd,
             float* __restrict__ out, int t)
{
  __shared__ __align__(16) float smem[11552];   // 46.2 KB

  if(blockIdx.x >= 128){
    // ---- gemm role: gparts(t+1), M=128 N=2048 K=512 split-K x4 ----
    float* As = smem;              // 16*68
    float* Bs = smem + 1088;
    const int g = blockIdx.x - 128;
    const int z = g >> 6, rem = g & 63;
    const int m0 = (rem & 1)*64, n0 = (rem >> 1)*64;
    const int tid = threadIdx.x;
    const int tx = tid & 15, ty = tid >> 4;
    const int kStart = z*128;
    float acc[4][4] = {};
    const int row = tid >> 2, kq = (tid & 3) * 4;
    for(int k0 = kStart; k0 < kStart + 128; k0 += 16){
      float4 av = *(const float4*)(h    + (size_t)(m0+row)*512 + k0 + kq);
      float4 bv = *(const float4*)(W_hh + (size_t)(n0+row)*512 + k0 + kq);
      As[(kq+0)*68+row]=av.x; As[(kq+1)*68+row]=av.y; As[(kq+2)*68+row]=av.z; As[(kq+3)*68+row]=av.w;
      Bs[(kq+0)*68+row]=bv.x; Bs[(kq+1)*68+row]=bv.y; Bs[(kq+2)*68+row]=bv.z; Bs[(kq+3)*68+row]=bv.w;
      __syncthreads();
      #pragma unroll
      for(int k=0;k<16;k++){
        float4 a = *(const float4*)&As[k*68 + 4*ty];
        float4 b = *(const float4*)&Bs[k*68 + 4*tx];
        acc[0][0]+=a.x*b.x; acc[0][1]+=a.x*b.y; acc[0][2]+=a.x*b.z; acc[0][3]+=a.x*b.w;
        acc[1][0]+=a.y*b.x; acc[1][1]+=a.y*b.y; acc[1][2]+=a.y*b.z; acc[1][3]+=a.y*b.w;
        acc[2][0]+=a.z*b.x; acc[2][1]+=a.z*b.y; acc[2][2]+=a.z*b.z; acc[2][3]+=a.z*b.w;
        acc[3][0]+=a.w*b.x; acc[3][1]+=a.w*b.y; acc[3][2]+=a.w*b.z; acc[3][3]+=a.w*b.w;
      }
      __syncthreads();
    }
    float* Cz = gparts + (size_t)z*262144;     // z * 2*64*2048
    #pragma unroll
    for(int i=0;i<4;i++){
      float4 o; o.x=acc[i][0]; o.y=acc[i][1]; o.z=acc[i][2]; o.w=acc[i][3];
      *(float4*)(Cz + (size_t)(m0+4*ty+i)*2048 + n0 + 4*tx) = o;
    }
    return;
  }

  // ---- scores+heads role ----
  float* tile   = smem;                               // 5*2048 logits (pre-patch, stays valid)
  float* kk     = smem + 10240;                       // 320: kr(256)+kw(64), tanh'd
  float* coef   = smem + 10560;                       // 5 (+3 pad): beta/||k||  (== coefR for heads 0-3)
  float* er     = smem + 10568;                       // 64
  float* ad     = smem + 10632;                       // 64
  float* nv     = smem + 10696;                       // 512: new rows at 8 write slots
  float* readsv = smem + 11208;                       // 256
  float* wstat  = smem + 11464;                       // 8: per-quarter (mx, Z) write head
  float* wval   = smem + 11472;                       // 8
  int*   widx   = (int*)(smem + 11480);               // 8
  unsigned long long* wcand = (unsigned long long*)(smem + 11488);  // 32 u64

  const int b = blockIdx.x, tid = threadIdx.x;
  const int lane = tid & 63, wave = tid >> 6;         // 4 waves
  const float* v = vc + (size_t)b*VC_;
  const size_t memb = (size_t)b*(size_t)(S_*M_);

  // P1: parameter transforms + phase-6 preloads
  float vt_o = v[tid];
  float brd_o = b_rd[tid];
  kk[tid] = tanhf(v[256+tid]);
  if(tid < 64){ kk[256+tid] = tanhf(v[516+tid]); er[tid] = sigmoidf_(v[581+tid]); ad[tid] = tanhf(v[645+tid]); }
  __syncthreads();
  if(tid < 5){
    float s = 0.f;
    #pragma unroll
    for(int m=0;m<64;m++){ float x = kk[tid*64+m]; s += x*x; }
    float beta = softplusf_( tid<4 ? v[512+tid] : v[580] );
    coef[tid] = beta / fmaxf(sqrtf(s), EPSF);
  }
  __syncthreads();

  // P2: logits for 8 slots/thread -> tile (LDS only; no global scores buffer)
  {
    const float4* kk4 = (const float4*)kk;
    #pragma unroll 2
    for(int q=0;q<8;q++){
      const int s = tid + q*256;
      const float4* row = (const float4*)(memC + memb + (size_t)s*M_);
      float nrm=0.f,d0=0.f,d1=0.f,d2=0.f,d3=0.f,dw=0.f;
      #pragma unroll
      for(int r4=0;r4<16;r4++){
        float4 xa = row[r4];
        float4 k0 = kk4[r4],    k1 = kk4[16+r4], k2 = kk4[32+r4];
        float4 k3 = kk4[48+r4], k4 = kk4[64+r4];
        nrm += xa.x*xa.x + xa.y*xa.y + xa.z*xa.z + xa.w*xa.w;
        d0  += xa.x*k0.x + xa.y*k0.y + xa.z*k0.z + xa.w*k0.w;
        d1  += xa.x*k1.x + xa.y*k1.y + xa.z*k1.z + xa.w*k1.w;
        d2  += xa.x*k2.x + xa.y*k2.y + xa.z*k2.z + xa.w*k2.w;
        d3  += xa.x*k3.x + xa.y*k3.y + xa.z*k3.z + xa.w*k3.w;
        dw  += xa.x*k4.x + xa.y*k4.y + xa.z*k4.z + xa.w*k4.w;
      }
      float inv = 1.0f / fmaxf(sqrtf(nrm), EPSF);
      tile[       s] = coef[0]*d0*inv;
      tile[2048 + s] = coef[1]*d1*inv;
      tile[4096 + s] = coef[2]*d2*inv;
      tile[6144 + s] = coef[3]*d3*inv;
      tile[8192 + s] = coef[4]*dw*inv;
    }
  }
  __syncthreads();

  // P3: candidates + stats. Wave r: read-head r global sorted top-16 (kept in regs)
  // + exact (max, sumexp) over 2048 (kept in regs). Also per-wave write-head quarter top-8.
  float mxR = 0.f, ZR = 0.f;
  unsigned long long T[16];
  {
    const int r = wave;
    const float* trow = tile + r*2048;
    unsigned long long X[16];
    #pragma unroll
    for(int j=0;j<16;j++){ int s = lane + j*64; X[j] = packCand(trow[s], (unsigned)s); }
    sort8(X); sort8(X+8); merge8x8(X);
    #pragma unroll
    for(int i=0;i<16;i++) T[i] = X[i];
    #pragma unroll
    for(int j=0;j<16;j++){ int s = lane + (16+j)*64; X[j] = packCand(trow[s], (unsigned)s); }
    sort8(X); sort8(X+8); merge8x8(X);
    keep16(T, X);
    butterfly16(T);                       // all lanes: global sorted top-16, head r
    // exact stats over 2048
    float mxl = -INFINITY;
    #pragma unroll
    for(int j=0;j<32;j++) mxl = fmaxf(mxl, trow[lane + j*64]);
    float sml = 0.f;
    #pragma unroll
    for(int j=0;j<32;j++) sml += expf(trow[lane + j*64] - mxl);
    float mxg = mxl;
    #pragma unroll
    for(int mask=1; mask<64; mask<<=1) mxg = fmaxf(mxg, __shfl_xor(mxg, mask, 64));
    float term = sml * expf(mxl - mxg);
    #pragma unroll
    for(int mask=1; mask<64; mask<<=1) term += __shfl_xor(term, mask, 64);
    mxR = mxg; ZR = term;
  }
  {
    // write head, quarter 'wave' (512 slots)
    const float* twow = tile + 4*2048 + wave*512;
    unsigned long long Wq[8];
    float x8[8];
    #pragma unroll
    for(int j=0;j<8;j++){ int s = lane + j*64; x8[j] = twow[s]; Wq[j] = packCand(x8[j], (unsigned)(wave*512 + s)); }
    sort8(Wq);
    butterfly8(Wq, 32);
    float mxl = x8[0];
    #pragma unroll
    for(int j=1;j<8;j++) mxl = fmaxf(mxl, x8[j]);
    float sml = 0.f;
    #pragma unroll
    for(int j=0;j<8;j++) sml += expf(x8[j] - mxl);
    float mxq = mxl;
    #pragma unroll
    for(int mask=1; mask<64; mask<<=1) mxq = fmaxf(mxq, __shfl_xor(mxq, mask, 64));
    float term = sml * expf(mxl - mxq);
    #pragma unroll
    for(int mask=1; mask<64; mask<<=1) term += __shfl_xor(term, mask, 64);
    if(lane == 0){
      #pragma unroll
      for(int p=0;p<8;p++) wcand[wave*8 + p] = Wq[p];
      wstat[wave*2] = mxq; wstat[wave*2+1] = term;
    }
  }
  __syncthreads();

  // P3b: wave 0 merges write-head quarters -> widx/wval
  if(wave == 0){
    float smx[4], ssm[4];
    #pragma unroll
    for(int c=0;c<4;c++){ smx[c] = wstat[c*2]; ssm[c] = wstat[c*2+1]; }
    float mxw = fmaxf(fmaxf(smx[0],smx[1]), fmaxf(smx[2],smx[3]));
    float Zw = ssm[0]*expf(smx[0]-mxw) + ssm[1]*expf(smx[1]-mxw)
             + ssm[2]*expf(smx[2]-mxw) + ssm[3]*expf(smx[3]-mxw);
    unsigned long long L[8];
    L[0] = (lane < 32) ? wcand[lane] : 0ULL;
    #pragma unroll
    for(int j=1;j<8;j++) L[j] = 0ULL;
    butterfly8(L, 16);
    if(lane == 0){
      float invZ = 1.0f / Zw;
      #pragma unroll
      for(int p=0;p<8;p++){
        widx[p] = (int)unpackIdx(L[p]);
        wval[p] = expf(unpackVal(L[p]) - mxw) * invZ;
      }
    }
  }
  __syncthreads();

  // P4: rank-1 erase/add at the 8 write slots (contiguous 256 B rows); tile stays pre-patch
  #pragma unroll
  for(int p=0;p<2;p++){
    int idx = tid + p*256;              // 512 = 8 slots x 64 dims
    int j = idx >> 6, m = idx & 63;
    int s = widx[j];
    float w = wval[j];
    size_t ptr = memb + (size_t)s*M_ + m;
    float old = memC[ptr];
    float x = old * (1.0f - w*er[m]) + w*ad[m];
    memC[ptr] = x;
    nv[j*64+m] = x;
  }
  __syncthreads();

  // P5: read heads — wave r patches its top-16, reselects top-8, exact Z', gathers
  {
    const int r = wave;
    const int sW = lane & 7, g = lane >> 3;
    const float4* nv4 = (const float4*)nv;
    const float4* kk4 = (const float4*)kk;
    float4 na = nv4[sW*16 + g*2], nb = nv4[sW*16 + g*2 + 1];
    float4 ka = kk4[r*16  + g*2], kb = kk4[r*16  + g*2 + 1];
    float dot = na.x*ka.x + na.y*ka.y + na.z*ka.z + na.w*ka.w
              + nb.x*kb.x + nb.y*kb.y + nb.z*kb.z + nb.w*kb.w;
    float n2  = na.x*na.x + na.y*na.y + na.z*na.z + na.w*na.w
              + nb.x*nb.x + nb.y*nb.y + nb.z*nb.z + nb.w*nb.w;
    #pragma unroll
    for(int mask=8; mask<64; mask<<=1){
      dot += __shfl_xor(dot, mask, 64);
      n2  += __shfl_xor(n2,  mask, 64);
    }
    float fixv = coef[r] * dot / fmaxf(sqrtf(n2), EPSF);
    int myw = widx[sW];

    // candidates: 16 pre-patch (kill written) + 8 written (new logits)
    unsigned long long eA = 0ULL;
    #pragma unroll
    for(int j=0;j<16;j++) if(j == lane) eA = T[j];
    if(lane < 16){
      unsigned idxA = unpackIdx(eA);
      bool kill = false;
      #pragma unroll
      for(int p=0;p<8;p++) kill = kill || (idxA == (unsigned)widx[p]);
      if(kill) eA = 0ULL;
    }
    unsigned long long eB = (lane < 8) ? packCand(fixv, (unsigned)myw) : 0ULL;
    unsigned long long L[8];
    L[0] = (eA > eB) ? eA : eB;
    L[1] = (eA > eB) ? eB : eA;
    #pragma unroll
    for(int j=2;j<8;j++) L[j] = 0ULL;
    butterfly8(L, 32);

    float mxS = fmaxf(mxR, unpackVal(L[0]));
    float Zp = ZR * expf(mxR - mxS);
    float oldv = (lane < 8) ? tile[r*2048 + myw] : 0.f;
    float adj = (lane < 8) ? (expf(fixv - mxS) - expf(oldv - mxS)) : 0.f;
    #pragma unroll
    for(int mask=1; mask<64; mask<<=1) adj += __shfl_xor(adj, mask, 64);
    float invZ = 1.0f / (Zp + adj);

    float acc = 0.f;                    // lane == mem dim m
    #pragma unroll
    for(int p=0;p<8;p++){
      float w = expf(unpackVal(L[p]) - mxS) * invZ;
      int si = (int)unpackIdx(L[p]);
      acc += w * memC[memb + (size_t)si*M_ + lane];
    }
    readsv[r*64 + lane] = acc;
  }

  // P6: out[b,t,:] = vt + reads @ W_rd^T + b_rd (32-wide batches, batch-0 prefetched)
  float wb[32];
  #pragma unroll
  for(int j=0;j<32;j++) wb[j] = WrdT[(size_t)j*256 + tid];
  __syncthreads();
  {
    float a0=0.f, a1=0.f, a2=0.f, a3=0.f;
    #pragma unroll
    for(int kb=0;kb<256;kb+=32){
      float wn[32];
      if(kb+32 < 256){
        #pragma unroll
        for(int j=0;j<32;j++) wn[j] = WrdT[(size_t)(kb+32+j)*256 + tid];
      }
      #pragma unroll
      for(int j=0;j<32;j+=4){
        a0 += readsv[kb+j  ]*wb[j  ];
        a1 += readsv[kb+j+1]*wb[j+1];
        a2 += readsv[kb+j+2]*wb[j+2];
        a3 += readsv[kb+j+3]*wb[j+3];
      }
      if(kb+32 < 256){
        #pragma unroll
        for(int j=0;j<32;j++) wb[j] = wn[j];
      }
    }
    out[((size_t)b*T_ + t)*(size_t)OUT_ + tid] = vt_o + brd_o + ((a0+a1)+(a2+a3));
  }
}

// ---------------- host ----------------
extern "C" void kernel_launch(void* const* d_in, const int* in_sizes, int n_in,
                              void* d_out, int out_size, void* d_ws, size_t ws_size,
                              hipStream_t stream)
{
  const float* x     = (const float*)d_in[0];
  const float* h0    = (const float*)d_in[1];
  const float* c0    = (const float*)d_in[2];
  const float* mem0  = (const float*)d_in[3];
  const float* W_ih  = (const float*)d_in[4];
  const float* W_hh  = (const float*)d_in[5];
  const float* b_ih  = (const float*)d_in[6];
  const float* b_hh  = (const float*)d_in[7];
  const float* W_out = (const float*)d_in[8];
  const float* b_out = (const float*)d_in[9];
  const float* W_rd  = (const float*)d_in[10];
  const float* b_rd  = (const float*)d_in[11];
  const float* W_head= (const float*)d_in[12];
  const float* b_head= (const float*)d_in[13];
  // d_in[14] = K (int) — fixed at 8 by the problem setup; hard-coded in k_fused.
  float* out = (float*)d_out;

  float* ws     = (float*)d_ws;
  float* memC   = ws;                    // 128*2048*64  = 16,777,216  (slot-major [B,S,M])
  float* xg     = memC   + 16777216;     // 128*32*2048  =  8,388,608
  float* gparts = xg     + 8388608;      // 4*128*2048   =  1,048,576
  float* vc     = gparts + 1048576;      // 128*712      =     91,136
  float* h      = vc     + 91136;        // 128*512      =     65,536
  float* c      = h      + 65536;        // 128*512      =     65,536
  float* WrdT   = c      + 65536;        // 256*256      =     65,536
  const size_t need = (size_t)(26502144) * sizeof(float);
  if(ws_size < need) return;  // ~101 MB workspace required

  hipMemcpyAsync(h, h0, 65536*sizeof(float), hipMemcpyDeviceToDevice, stream);
  hipMemcpyAsync(c, c0, 65536*sizeof(float), hipMemcpyDeviceToDevice, stream);
  hipMemcpyAsync(memC, mem0, (size_t)16777216*sizeof(float), hipMemcpyDeviceToDevice, stream);
  k_transpose_rd<<<256,256,0,stream>>>(W_rd, WrdT);
  // xg[b*T+t, :] = x @ W_ih^T + (b_ih+b_hh)  — hoisted out of the time loop
  k_gemm64<<<dim3(64,32,1),256,0,stream>>>(x,256, W_ih,256, xg,2048, 256, b_ih,b_hh);
  // gparts(0) = h0 @ W_hh^T  (split-K x4)
  k_gemm64<<<dim3(2,32,4),256,0,stream>>>(h,512, W_hh,512, gparts,2048, 128, nullptr,nullptr);

  for(int t=0;t<T_;t++){
    k_lstm<<<256,256,0,stream>>>(xg, gparts, h, c, t);
    k_vtctrl<<<dim3(4,23),256,0,stream>>>(h, W_out,b_out, W_head,b_head, vc);
    // fused: scores+heads(t) blocks 0-127  ||  gparts(t+1) gemm blocks 128-383
    k_fused<<<384,256,0,stream>>>(memC, vc, h, W_hh, gparts, WrdT, b_rd, out, t);
  }
}

// Round 4
// 1846.721 us; speedup vs baseline: 1.6447x; 1.6447x over previous
//
#include <hip/hip_runtime.h>
#include <math.h>

#define DEV __device__ __forceinline__

static constexpr int B_ = 128, T_ = 32, H_ = 512;
static constexpr int S_ = 2048, M_ = 64, OUT_ = 256;
static constexpr int VC_ = 712;   // 256 (vt) + 453 (ctrl), padded to 712
static constexpr float EPSF = 1e-8f;

DEV float sigmoidf_(float x){ return 1.0f/(1.0f+expf(-x)); }
DEV float softplusf_(float x){ return fmaxf(x,0.0f) + log1pf(expf(-fabsf(x))); }

// ---- packed candidate: (monotonic(value) << 32) | ~idx  => u64 '>' == (value desc, idx asc)
DEV unsigned long long packCand(float v, unsigned idx){
  unsigned u = __float_as_uint(v);
  unsigned m = (u & 0x80000000u) ? ~u : (u | 0x80000000u);
  return ((unsigned long long)m << 32) | (unsigned)(~idx);
}
DEV float unpackVal(unsigned long long e){
  unsigned m = (unsigned)(e >> 32);
  unsigned u = (m & 0x80000000u) ? (m & 0x7FFFFFFFu) : ~m;
  return __uint_as_float(u);
}
DEV unsigned unpackIdx(unsigned long long e){ return ~(unsigned)e; }

DEV void cswp(unsigned long long &a, unsigned long long &b){
  if(a < b){ unsigned long long t=a; a=b; b=t; }   // larger first (descending)
}
// Batcher odd-even mergesort for 8, descending
DEV void sort8(unsigned long long* L){
  cswp(L[0],L[1]); cswp(L[2],L[3]); cswp(L[4],L[5]); cswp(L[6],L[7]);
  cswp(L[0],L[2]); cswp(L[1],L[3]); cswp(L[4],L[6]); cswp(L[5],L[7]);
  cswp(L[1],L[2]); cswp(L[5],L[6]);
  cswp(L[0],L[4]); cswp(L[1],L[5]); cswp(L[2],L[6]); cswp(L[3],L[7]);
  cswp(L[2],L[4]); cswp(L[3],L[5]);
  cswp(L[1],L[2]); cswp(L[3],L[4]); cswp(L[5],L[6]);
}
// bitonic merge of 16, descending (input must be bitonic)
DEV void bmerge16(unsigned long long* C){
  #pragma unroll
  for(int i=0;i<8;i++) cswp(C[i],C[i+8]);
  #pragma unroll
  for(int g=0;g<2;g++){ int o=g*8;
    cswp(C[o+0],C[o+4]); cswp(C[o+1],C[o+5]); cswp(C[o+2],C[o+6]); cswp(C[o+3],C[o+7]); }
  #pragma unroll
  for(int g=0;g<4;g++){ int o=g*4; cswp(C[o+0],C[o+2]); cswp(C[o+1],C[o+3]); }
  #pragma unroll
  for(int g=0;g<8;g++){ int o=g*2; cswp(C[o],C[o+1]); }
}
// X[0..7] desc, X[8..15] desc -> X[0..15] fully sorted desc
DEV void merge8x8(unsigned long long* X){
  unsigned long long C[16];
  #pragma unroll
  for(int i=0;i<8;i++){ C[i]=X[i]; C[8+i]=X[15-i]; }
  bmerge16(C);
  #pragma unroll
  for(int i=0;i<16;i++) X[i]=C[i];
}
// butterfly keep-8: each lane holds sorted-8 desc
DEV void butterfly8(unsigned long long* L, int maxMask){
  for(int mask=1; mask<=maxMask; mask<<=1){
    unsigned long long O[8], C[8];
    #pragma unroll
    for(int i=0;i<8;i++) O[i] = __shfl_xor(L[i], mask, 64);
    #pragma unroll
    for(int i=0;i<8;i++){ unsigned long long a=L[i], b=O[7-i]; C[i] = (a>b)?a:b; }
    cswp(C[0],C[4]); cswp(C[1],C[5]); cswp(C[2],C[6]); cswp(C[3],C[7]);
    cswp(C[0],C[2]); cswp(C[1],C[3]); cswp(C[4],C[6]); cswp(C[5],C[7]);
    cswp(C[0],C[1]); cswp(C[2],C[3]); cswp(C[4],C[5]); cswp(C[6],C[7]);
    #pragma unroll
    for(int i=0;i<8;i++) L[i]=C[i];
  }
}
// butterfly keep-16 over all 64 lanes (per-lane lists sorted-16 desc)
DEV void butterfly16(unsigned long long* L){
  for(int mask=1; mask<64; mask<<=1){
    unsigned long long O[16], C[16];
    #pragma unroll
    for(int i=0;i<16;i++) O[i] = __shfl_xor(L[i], mask, 64);
    #pragma unroll
    for(int i=0;i<16;i++){ unsigned long long a=L[i], b=O[15-i]; C[i] = (a>b)?a:b; }
    bmerge16(C);
    #pragma unroll
    for(int i=0;i<16;i++) L[i]=C[i];
  }
}

// ---------------- preamble: W_rd [256,256] -> W_rdT ----------------
__global__ __launch_bounds__(256)
void k_transpose_rd(const float* __restrict__ W, float* __restrict__ WT){
  int idx = blockIdx.x*256 + threadIdx.x;  // 65536
  int k = idx>>8, o = idx&255;
  WT[k*256+o] = W[o*256+k];
}

// ---------------- generic fp32 GEMM  C[M,N] = A[M,K] * Bm[N,K]^T ----------------
__global__ __launch_bounds__(256)
void k_gemm64(const float* __restrict__ A, int lda,
              const float* __restrict__ Bm, int ldb,
              float* __restrict__ C, int ldc,
              int kCount,
              const float* __restrict__ bias0, const float* __restrict__ bias1)
{
  const int BM=64, BN=64, BK=16, LDT=68;
  __shared__ float As[BK*LDT];
  __shared__ float Bs[BK*LDT];
  const int m0 = blockIdx.x*BM, n0 = blockIdx.y*BN;
  const int tid = threadIdx.x;
  const int tx = tid & 15, ty = tid >> 4;
  const int kStart = blockIdx.z * kCount;
  float acc[4][4] = {};
  const int row = tid >> 2, kk = (tid & 3) * 4;
  for(int k0 = kStart; k0 < kStart + kCount; k0 += BK){
    float4 av = *(const float4*)(A  + (size_t)(m0+row)*lda + k0 + kk);
    float4 bv = *(const float4*)(Bm + (size_t)(n0+row)*ldb + k0 + kk);
    As[(kk+0)*LDT+row]=av.x; As[(kk+1)*LDT+row]=av.y; As[(kk+2)*LDT+row]=av.z; As[(kk+3)*LDT+row]=av.w;
    Bs[(kk+0)*LDT+row]=bv.x; Bs[(kk+1)*LDT+row]=bv.y; Bs[(kk+2)*LDT+row]=bv.z; Bs[(kk+3)*LDT+row]=bv.w;
    __syncthreads();
    #pragma unroll
    for(int k=0;k<BK;k++){
      float4 a = *(const float4*)&As[k*LDT + 4*ty];
      float4 b = *(const float4*)&Bs[k*LDT + 4*tx];
      acc[0][0]+=a.x*b.x; acc[0][1]+=a.x*b.y; acc[0][2]+=a.x*b.z; acc[0][3]+=a.x*b.w;
      acc[1][0]+=a.y*b.x; acc[1][1]+=a.y*b.y; acc[1][2]+=a.y*b.z; acc[1][3]+=a.y*b.w;
      acc[2][0]+=a.z*b.x; acc[2][1]+=a.z*b.y; acc[2][2]+=a.z*b.z; acc[2][3]+=a.z*b.w;
      acc[3][0]+=a.w*b.x; acc[3][1]+=a.w*b.y; acc[3][2]+=a.w*b.z; acc[3][3]+=a.w*b.w;
    }
    __syncthreads();
  }
  float* Cz = C + (size_t)blockIdx.z * (size_t)gridDim.x * BM * (size_t)ldc;
  #pragma unroll
  for(int i=0;i<4;i++){
    int m = m0 + 4*ty + i;
    int n = n0 + 4*tx;
    float4 o; o.x=acc[i][0]; o.y=acc[i][1]; o.z=acc[i][2]; o.w=acc[i][3];
    if(bias0){
      o.x += bias0[n]+bias1[n];     o.y += bias0[n+1]+bias1[n+1];
      o.z += bias0[n+2]+bias1[n+2]; o.w += bias0[n+3]+bias1[n+3];
    }
    *(float4*)(Cz + (size_t)m*ldc + n) = o;
  }
}

// ---------------- phase A: LSTM elementwise (writes h into h_all slice) ----------------
__global__ __launch_bounds__(256)
void k_lstm(const float* __restrict__ xg, const float* __restrict__ gp,
            float* __restrict__ hout, float* __restrict__ c, int t)
{
  int idx = blockIdx.x*256 + threadIdx.x;   // 65536 = 128*512
  int b = idx >> 9, j = idx & 511;
  const float* xr = xg + ((size_t)b*T_ + t)*(size_t)(4*H_);
  float gi = xr[j], gf = xr[512+j], gg = xr[1024+j], go = xr[1536+j];
  #pragma unroll
  for(int s4=0;s4<4;s4++){
    const float* pr = gp + ((size_t)s4*B_ + b)*(size_t)(4*H_);
    gi += pr[j]; gf += pr[512+j]; gg += pr[1024+j]; go += pr[1536+j];
  }
  float cc = sigmoidf_(gf)*c[idx] + sigmoidf_(gi)*tanhf(gg);
  float hh = sigmoidf_(go)*tanhf(cc);
  c[idx] = cc; hout[idx] = hh;
}

// ---------------- vt+ctrl GEMM  [M,712] = h[M,512] @ cat(W_out,W_head)^T ----------------
// Launched once with M=4096 (all t,b) after phase A.
__global__ __launch_bounds__(256)
void k_vtctrl(const float* __restrict__ h, const float* __restrict__ Wout,
              const float* __restrict__ bout, const float* __restrict__ Whead,
              const float* __restrict__ bhead, float* __restrict__ vc)
{
  const int BM=32, BN=32, BK=16, LDT=34;
  __shared__ float As[BK*LDT], Bs[BK*LDT];
  const int m0 = blockIdx.x*BM, n0 = blockIdx.y*BN;
  const int tid = threadIdx.x, tx = tid&15, ty = tid>>4;
  float acc[2][2] = {};
  for(int k0=0;k0<512;k0+=BK){
    #pragma unroll
    for(int p=0;p<2;p++){
      int idx = tid + p*256;
      int r = idx>>4, kq = idx&15;
      As[kq*LDT+r] = h[(size_t)(m0+r)*512 + k0+kq];
      int j = n0 + r;
      float v = 0.f;
      if(j < 256)      v = Wout[(size_t)j*512 + k0+kq];
      else if(j < 709) v = Whead[(size_t)(j-256)*512 + k0+kq];
      Bs[kq*LDT+r] = v;
    }
    __syncthreads();
    #pragma unroll
    for(int k=0;k<BK;k++){
      float2 a = *(const float2*)&As[k*LDT + 2*ty];
      float2 b = *(const float2*)&Bs[k*LDT + 2*tx];
      acc[0][0]+=a.x*b.x; acc[0][1]+=a.x*b.y; acc[1][0]+=a.y*b.x; acc[1][1]+=a.y*b.y;
    }
    __syncthreads();
  }
  #pragma unroll
  for(int i=0;i<2;i++){
    int m = m0 + 2*ty + i;
    #pragma unroll
    for(int j2=0;j2<2;j2++){
      int n = n0 + 2*tx + j2;
      if(n < VC_){
        float bv = 0.f;
        if(n < 256) bv = bout[n]; else if(n < 709) bv = bhead[n-256];
        vc[(size_t)m*VC_ + n] = (n < 709) ? acc[i][j2] + bv : 0.f;
      }
    }
  }
}

// ---------------- phase B: logits + per-chunk stats + per-chunk topk candidates ----------------
// grid (128, 4), 512 threads (8 waves). One slot per thread; then per-wave tasks:
// waves 0-3: sorted top-16 candidates for read heads 0-3; wave 4: sorted top-8 for write head;
// waves 5-7: (max, sum-exp) stats for heads {0,1},{2,3},{4}. No global logit store.
__global__ __launch_bounds__(512,4)
void k_scores(const float* __restrict__ memC, const float* __restrict__ vcAll, int t,
              unsigned long long* __restrict__ candW,
              unsigned long long* __restrict__ candR,
              float* __restrict__ statsB)
{
  __shared__ float kk[5*64];
  __shared__ float coef[5];
  __shared__ float tile[5*512];
  const int b = blockIdx.x, ch = blockIdx.y, tid = threadIdx.x;
  const int lane = tid & 63, wid = tid >> 6;
  const float* v = vcAll + ((size_t)t*B_ + b)*VC_;
  if(tid < 256) kk[tid] = tanhf(v[256+tid]);           // kr (4x64)
  else if(tid < 320) kk[tid] = tanhf(v[516 + tid-256]);// kw (64)
  __syncthreads();
  if(tid < 5){
    float s = 0.f;
    #pragma unroll
    for(int m=0;m<64;m++){ float x = kk[tid*64+m]; s += x*x; }
    float beta = softplusf_( tid<4 ? v[512+tid] : v[580] );
    coef[tid] = beta / fmaxf(sqrtf(s), EPSF);
  }
  __syncthreads();

  // logits for this thread's slot
  {
    const int s = ch*512 + tid;
    const float4* row = (const float4*)(memC + ((size_t)b*S_ + s)*M_);
    float nrm=0.f, d0=0.f, d1=0.f, d2=0.f, d3=0.f, dw=0.f;
    #pragma unroll
    for(int r4=0;r4<16;r4++){
      float4 xa = row[r4];
      float av[4] = {xa.x,xa.y,xa.z,xa.w};
      #pragma unroll
      for(int j=0;j<4;j++){
        const int m = r4*4+j;
        float a = av[j];
        nrm += a*a;
        d0 += a*kk[m];     d1 += a*kk[64+m]; d2 += a*kk[128+m];
        d3 += a*kk[192+m]; dw += a*kk[256+m];
      }
    }
    float inv = 1.0f / fmaxf(sqrtf(nrm), EPSF);
    tile[0*512+tid] = coef[0]*d0*inv;
    tile[1*512+tid] = coef[1]*d1*inv;
    tile[2*512+tid] = coef[2]*d2*inv;
    tile[3*512+tid] = coef[3]*d3*inv;
    tile[4*512+tid] = coef[4]*dw*inv;
  }
  __syncthreads();

  if(wid < 4){
    // read head wid: sorted top-16 of this chunk
    unsigned long long L[16];
    #pragma unroll
    for(int j=0;j<8;j++){
      int i = lane + j*64;
      L[j] = packCand(tile[wid*512 + i], (unsigned)(ch*512 + i));
    }
    sort8(L);
    #pragma unroll
    for(int j=8;j<16;j++) L[j] = 0ULL;
    butterfly16(L);
    if(lane == 0){
      unsigned long long* dst = candR + (((size_t)b*4 + ch)*4 + wid)*16;
      #pragma unroll
      for(int j=0;j<16;j++) dst[j] = L[j];
    }
  } else if(wid == 4){
    // write head: sorted top-8 of this chunk
    unsigned long long L[8];
    #pragma unroll
    for(int j=0;j<8;j++){
      int i = lane + j*64;
      L[j] = packCand(tile[4*512 + i], (unsigned)(ch*512 + i));
    }
    sort8(L);
    butterfly8(L, 32);
    if(lane == 0){
      unsigned long long* dst = candW + ((size_t)b*4 + ch)*8;
      #pragma unroll
      for(int j=0;j<8;j++) dst[j] = L[j];
    }
  } else {
    // stats waves: wid 5 -> heads 0,1; wid 6 -> heads 2,3; wid 7 -> head 4
    int h0 = (wid==5) ? 0 : (wid==6) ? 2 : 4;
    int nh = (wid==7) ? 1 : 2;
    for(int q=0;q<nh;q++){
      int h = h0 + q;
      float x[8];
      #pragma unroll
      for(int j=0;j<8;j++) x[j] = tile[h*512 + lane + j*64];
      float mx = x[0];
      #pragma unroll
      for(int j=1;j<8;j++) mx = fmaxf(mx, x[j]);
      #pragma unroll
      for(int mask=1; mask<64; mask<<=1) mx = fmaxf(mx, __shfl_xor(mx, mask, 64));
      float sm = 0.f;
      #pragma unroll
      for(int j=0;j<8;j++) sm += expf(x[j]-mx);
      #pragma unroll
      for(int mask=1; mask<64; mask<<=1) sm += __shfl_xor(sm, mask, 64);
      if(lane == 0){
        float* st = statsB + (((size_t)b*4 + ch)*5 + h)*2;
        st[0] = mx; st[1] = sm;
      }
    }
  }
}

// ---------------- phase B: write head + mem update + read heads + output ----------------
__global__ __launch_bounds__(256)
void k_heads(float* __restrict__ memC,
             const float* __restrict__ vcAll,
             const unsigned long long* __restrict__ candW,
             const unsigned long long* __restrict__ candR,
             const float* __restrict__ statsB,
             const float* __restrict__ WrdT,
             const float* __restrict__ b_rd,
             float* __restrict__ out, int t)
{
  __shared__ __align__(16) float kr[256];
  __shared__ float er[64], ad[64];
  __shared__ float coefR[4];
  __shared__ __align__(16) float nv[512];
  __shared__ __align__(16) float oldrow[512];
  __shared__ int   widx[8];
  __shared__ float wval[8];
  __shared__ float readsv[256];

  const int b = blockIdx.x, tid = threadIdx.x;
  const int lane = tid & 63, wave = tid >> 6;
  const float* v = vcAll + ((size_t)t*B_ + b)*VC_;
  const size_t memb = (size_t)b*(size_t)S_*M_;

  // phase 1: parameter transforms (+ early loads for phase 6)
  float vt_o = v[tid];
  float brd_o = b_rd[tid];
  kr[tid] = tanhf(v[256+tid]);
  if(tid < 64){ er[tid] = sigmoidf_(v[581+tid]); ad[tid] = tanhf(v[645+tid]); }
  __syncthreads();

  // phase 2: write-head selection (wave 0), coefR (wave 1)
  if(wave == 0){
    float smx[4], ssm[4];
    #pragma unroll
    for(int c=0;c<4;c++){
      const float* st = statsB + (((size_t)b*4 + c)*5 + 4)*2;
      smx[c] = st[0]; ssm[c] = st[1];
    }
    float mxw = fmaxf(fmaxf(smx[0],smx[1]), fmaxf(smx[2],smx[3]));
    float Zw = ssm[0]*expf(smx[0]-mxw) + ssm[1]*expf(smx[1]-mxw)
             + ssm[2]*expf(smx[2]-mxw) + ssm[3]*expf(smx[3]-mxw);
    unsigned long long L[8];
    L[0] = (lane < 32) ? candW[((size_t)b*4 + (lane>>3))*8 + (lane&7)] : 0ULL;
    #pragma unroll
    for(int j=1;j<8;j++) L[j] = 0ULL;
    butterfly8(L, 16);                 // lanes 0-31 contain the data; 5 steps suffice
    if(lane == 0){
      float invZ = 1.0f / Zw;
      #pragma unroll
      for(int p=0;p<8;p++){
        widx[p] = (int)unpackIdx(L[p]);
        wval[p] = expf(unpackVal(L[p]) - mxw) * invZ;
      }
    }
  } else if(wave == 1 && lane < 4){
    float s = 0.f;
    #pragma unroll
    for(int m=0;m<64;m++){ float x = kr[lane*64+m]; s += x*x; }
    coefR[lane] = softplusf_(v[512+lane]) / fmaxf(sqrtf(s), EPSF);
  }
  __syncthreads();

  // phase 3: rank-1 erase/add at the 8 write slots; stash OLD rows for the Z adjustment
  #pragma unroll
  for(int p=0;p<2;p++){
    int idx = tid + p*256;              // 512 = 8 slots x 64 dims
    int j = idx >> 6, m = idx & 63;
    int s = widx[j];
    float w = wval[j];
    size_t ptr = memb + (size_t)s*M_ + m;
    float old = memC[ptr];
    oldrow[j*64+m] = old;
    float x = old * (1.0f - w*er[m]) + w*ad[m];
    memC[ptr] = x;
    nv[j*64+m] = x;
  }
  __syncthreads();

  // phases 4+5 fused, one wave per read head r
  {
    const int r = wave;
    const int sW = lane & 7, g = lane >> 3;
    const float4* nv4 = (const float4*)nv;
    const float4* ov4 = (const float4*)oldrow;
    const float4* kr4 = (const float4*)kr;
    float4 na = nv4[sW*16 + g*2], nb = nv4[sW*16 + g*2 + 1];
    float4 oa = ov4[sW*16 + g*2], ob = ov4[sW*16 + g*2 + 1];
    float4 ka = kr4[r*16  + g*2], kb = kr4[r*16  + g*2 + 1];
    float dot = na.x*ka.x + na.y*ka.y + na.z*ka.z + na.w*ka.w
              + nb.x*kb.x + nb.y*kb.y + nb.z*kb.z + nb.w*kb.w;
    float n2  = na.x*na.x + na.y*na.y + na.z*na.z + na.w*na.w
              + nb.x*nb.x + nb.y*nb.y + nb.z*nb.z + nb.w*nb.w;
    float odot= oa.x*ka.x + oa.y*ka.y + oa.z*ka.z + oa.w*ka.w
              + ob.x*kb.x + ob.y*kb.y + ob.z*kb.z + ob.w*kb.w;
    float on2 = oa.x*oa.x + oa.y*oa.y + oa.z*oa.z + oa.w*oa.w
              + ob.x*ob.x + ob.y*ob.y + ob.z*ob.z + ob.w*ob.w;
    #pragma unroll
    for(int mask=8; mask<64; mask<<=1){
      dot  += __shfl_xor(dot,  mask, 64);
      n2   += __shfl_xor(n2,   mask, 64);
      odot += __shfl_xor(odot, mask, 64);
      on2  += __shfl_xor(on2,  mask, 64);
    }
    float fixv = coefR[r] * dot  / fmaxf(sqrtf(n2),  EPSF);
    float oldv = coefR[r] * odot / fmaxf(sqrtf(on2), EPSF);  // pre-patch read logit @ written slot
    int myw = widx[sW];

    // pre-patch chunk stats for this head
    float scx[4], scs[4];
    #pragma unroll
    for(int c=0;c<4;c++){
      const float* st = statsB + (((size_t)b*4 + c)*5 + r)*2;
      scx[c] = st[0]; scs[c] = st[1];
    }
    float mxp = fmaxf(fmaxf(scx[0],scx[1]), fmaxf(scx[2],scx[3]));

    // candidates: 64 chunk entries (invalidate written) + 8 written entries with new logits
    unsigned long long L[8];
    {
      int c = lane >> 4, rank = lane & 15;
      unsigned long long eA = candR[(((size_t)b*4 + c)*4 + r)*16 + rank];
      unsigned idxA = unpackIdx(eA);
      bool kill = false;
      #pragma unroll
      for(int p=0;p<8;p++) kill = kill || (idxA == (unsigned)widx[p]);
      if(kill) eA = 0ULL;
      unsigned long long eB = (lane < 8) ? packCand(fixv, (unsigned)myw) : 0ULL;
      L[0] = (eA > eB) ? eA : eB;
      L[1] = (eA > eB) ? eB : eA;
      #pragma unroll
      for(int j=2;j<8;j++) L[j] = 0ULL;
    }
    butterfly8(L, 32);                 // all lanes -> global post-patch sorted top-8

    // exact denominator: Z' = Z_pre(mxS) - sum exp(old) + sum exp(new)
    float mxS = fmaxf(mxp, unpackVal(L[0]));
    float Zp = scs[0]*expf(scx[0]-mxS) + scs[1]*expf(scx[1]-mxS)
             + scs[2]*expf(scx[2]-mxS) + scs[3]*expf(scx[3]-mxS);
    float adj = (lane < 8) ? (expf(fixv - mxS) - expf(oldv - mxS)) : 0.f;
    #pragma unroll
    for(int mask=1; mask<64; mask<<=1) adj += __shfl_xor(adj, mask, 64);
    float invZ = 1.0f / (Zp + adj);

    float acc = 0.f;                   // lane == mem dim m
    #pragma unroll
    for(int p=0;p<8;p++){
      float w = expf(unpackVal(L[p]) - mxS) * invZ;
      int si = (int)unpackIdx(L[p]);
      acc += w * memC[memb + (size_t)si*M_ + lane];   // new mem, contiguous row
    }
    readsv[r*64 + lane] = acc;
  }

  // phase 6: out[b,t,:] = vt + reads @ W_rd^T + b_rd (32-wide batches, batch-0 prefetched)
  float wb[32];
  #pragma unroll
  for(int j=0;j<32;j++) wb[j] = WrdT[(size_t)j*256 + tid];
  __syncthreads();
  {
    float a0=0.f, a1=0.f, a2=0.f, a3=0.f;
    #pragma unroll
    for(int kb=0;kb<256;kb+=32){
      float wn[32];
      if(kb+32 < 256){
        #pragma unroll
        for(int j=0;j<32;j++) wn[j] = WrdT[(size_t)(kb+32+j)*256 + tid];
      }
      #pragma unroll
      for(int j=0;j<32;j+=4){
        a0 += readsv[kb+j  ]*wb[j  ];
        a1 += readsv[kb+j+1]*wb[j+1];
        a2 += readsv[kb+j+2]*wb[j+2];
        a3 += readsv[kb+j+3]*wb[j+3];
      }
      if(kb+32 < 256){
        #pragma unroll
        for(int j=0;j<32;j++) wb[j] = wn[j];
      }
    }
    out[((size_t)b*T_ + t)*(size_t)OUT_ + tid] = vt_o + brd_o + ((a0+a1)+(a2+a3));
  }
}

// ---------------- host ----------------
extern "C" void kernel_launch(void* const* d_in, const int* in_sizes, int n_in,
                              void* d_out, int out_size, void* d_ws, size_t ws_size,
                              hipStream_t stream)
{
  const float* x     = (const float*)d_in[0];
  const float* h0    = (const float*)d_in[1];
  const float* c0    = (const float*)d_in[2];
  const float* mem0  = (const float*)d_in[3];
  const float* W_ih  = (const float*)d_in[4];
  const float* W_hh  = (const float*)d_in[5];
  const float* b_ih  = (const float*)d_in[6];
  const float* b_hh  = (const float*)d_in[7];
  const float* W_out = (const float*)d_in[8];
  const float* b_out = (const float*)d_in[9];
  const float* W_rd  = (const float*)d_in[10];
  const float* b_rd  = (const float*)d_in[11];
  const float* W_head= (const float*)d_in[12];
  const float* b_head= (const float*)d_in[13];
  // d_in[14] = K (int) — fixed at 8 by the problem setup; hard-coded in k_heads.
  float* out = (float*)d_out;

  float* ws     = (float*)d_ws;
  float* memC   = ws;                    // 128*2048*64  = 16,777,216  (slot-major [B,S,M])
  float* xg     = memC   + 16777216;     // 128*32*2048  =  8,388,608  (phase A only)
  float* gparts = xg     + 8388608;      // 4*128*2048   =  1,048,576  (phase A only)
  float* h_all  = gparts + 1048576;      // 32*128*512   =  2,097,152
  float* c      = h_all  + 2097152;      // 128*512      =     65,536
  float* WrdT   = c      + 65536;        // 256*256      =     65,536
  // vc_all [32*128, 712] overlays xg (dead after phase A): 2,916,352 <= 8,388,608
  float* vc_all = xg;
  // candidate/stat buffers overlay gparts (dead after phase A):
  unsigned long long* candW  = (unsigned long long*)gparts;     // 128*4*8  u64
  unsigned long long* candR  = candW + 4096;                    // 128*4*4*16 u64
  float*              statsB = (float*)(candR + 32768);         // 128*4*5*2 floats
  const size_t need = (size_t)(28442624) * sizeof(float);
  if(ws_size < need) return;  // ~114 MB workspace required

  hipMemcpyAsync(c, c0, 65536*sizeof(float), hipMemcpyDeviceToDevice, stream);
  hipMemcpyAsync(memC, mem0, (size_t)16777216*sizeof(float), hipMemcpyDeviceToDevice, stream);
  k_transpose_rd<<<256,256,0,stream>>>(W_rd, WrdT);
  // xg[b*T+t, :] = x @ W_ih^T + (b_ih+b_hh)
  k_gemm64<<<dim3(64,32,1),256,0,stream>>>(x,256, W_ih,256, xg,2048, 256, b_ih,b_hh);

  // ---- phase A: LSTM recurrence (independent of memory) -> h_all ----
  for(int t=0;t<T_;t++){
    const float* hprev = (t == 0) ? h0 : (h_all + (size_t)(t-1)*65536);
    k_gemm64<<<dim3(2,32,4),256,0,stream>>>(hprev,512, W_hh,512, gparts,2048, 128, nullptr,nullptr);
    k_lstm<<<256,256,0,stream>>>(xg, gparts, h_all + (size_t)t*65536, c, t);
  }
  // ---- all vt+ctrl in one batched GEMM: [4096,712] = h_all @ cat(W_out,W_head)^T ----
  k_vtctrl<<<dim3(128,23),256,0,stream>>>(h_all, W_out,b_out, W_head,b_head, vc_all);

  // ---- phase B: memory loop ----
  for(int t=0;t<T_;t++){
    k_scores<<<dim3(128,4),512,0,stream>>>(memC, vc_all, t, candW, candR, statsB);
    k_heads<<<128,256,0,stream>>>(memC, vc_all, candW, candR, statsB, WrdT, b_rd, out, t);
  }
}